// Round 1
// baseline (258.878 us; speedup 1.0000x reference)
//
#include <hip/hip_runtime.h>
#include <hip/hip_fp16.h>
#include <cstdint>
#include <cstddef>

// VideoSAGE: proj GEMM -> 3x (GCN GEMM + tridiag band mix) -> s1 -> s2 -> dot+sigmoid
// Strategy: fp16 MFMA (16x16x32) with fp32 accumulate everywhere.
// All GEMMs consume A[M,K] and BT[N,K], both K-major fp16 (weights pre-transposed).

typedef _Float16 f16;
typedef _Float16 f16x8 __attribute__((ext_vector_type(8)));
typedef float    f32x4 __attribute__((ext_vector_type(4)));

__device__ __forceinline__ void async_cp16(const void* g, void* l) {
  __builtin_amdgcn_global_load_lds((const __attribute__((address_space(1))) void*)g,
                                   (__attribute__((address_space(3))) void*)l, 16, 0, 0);
}

// ---------------------------------------------------------------------------
// GEMM: C[M,N] = act(A[M,K] * BT[N,K]^T + bias)
// 256 threads = 4 waves. Wave tile WM x WN (TMxTN grid of 16x16 MFMA tiles).
// LDS: [rows][BK=64] halfs, 16B chunks XOR-swizzled (swizzle applied on the
// GLOBAL chunk index so global_load_lds's lane-linear LDS dest is preserved).
// ---------------------------------------------------------------------------
template<int BM, int BN, int WAVES_M, int WAVES_N, bool RELU, bool HAS_BIAS>
__global__ __launch_bounds__(256) void gemm_f16_kernel(
    const f16* __restrict__ A, const f16* __restrict__ BT,
    f16* __restrict__ C, const float* __restrict__ bias,
    int M, int N, int K)
{
  constexpr int BK = 64;
  constexpr int WM = BM / WAVES_M;
  constexpr int WN = BN / WAVES_N;
  constexpr int TM = WM / 16;
  constexpr int TN = WN / 16;
  constexpr int ITER_A = (BM * BK) / (256 * 8);
  constexpr int ITER_B = (BN * BK) / (256 * 8);

  __shared__ __align__(16) f16 sA[BM * BK];
  __shared__ __align__(16) f16 sB[BN * BK];

  const int tid  = threadIdx.x;
  const int lane = tid & 63;
  const int wave = tid >> 6;
  const int wm   = wave / WAVES_N;
  const int wn   = wave % WAVES_N;
  const int m0   = blockIdx.x * BM;
  const int n0   = blockIdx.y * BN;

  f32x4 acc[TM][TN];
#pragma unroll
  for (int i = 0; i < TM; ++i)
#pragma unroll
    for (int j = 0; j < TN; ++j)
      acc[i][j] = (f32x4){0.f, 0.f, 0.f, 0.f};

  const int quad = lane >> 4;
  const int l16  = lane & 15;

  for (int kt = 0; kt < K; kt += BK) {
    __syncthreads();   // previous iter's LDS reads complete before overwrite
#pragma unroll
    for (int j = 0; j < ITER_A; ++j) {
      const int linear = j * 256 + tid;       // 16B chunk id, lane-linear
      const int row = linear >> 3;            // 8 chunks per 64-half row
      const int q   = (linear & 7) ^ (row & 7);  // swizzled GLOBAL chunk
      async_cp16(A + (size_t)(m0 + row) * K + kt + q * 8, &sA[linear * 8]);
    }
#pragma unroll
    for (int j = 0; j < ITER_B; ++j) {
      const int linear = j * 256 + tid;
      const int row = linear >> 3;
      const int q   = (linear & 7) ^ (row & 7);
      async_cp16(BT + (size_t)(n0 + row) * K + kt + q * 8, &sB[linear * 8]);
    }
    __syncthreads();   // compiler emits vmcnt(0) drain before barrier

#pragma unroll
    for (int kk = 0; kk < 2; ++kk) {          // two K=32 steps per BK=64
      const int c = quad + kk * 4;            // 16B chunk within row
      f16x8 af[TM], bf[TN];
#pragma unroll
      for (int mi = 0; mi < TM; ++mi) {
        const int ml = wm * WM + mi * 16 + l16;
        af[mi] = *(const f16x8*)&sA[ml * 64 + ((c ^ (ml & 7)) * 8)];
      }
#pragma unroll
      for (int ni = 0; ni < TN; ++ni) {
        const int nl = wn * WN + ni * 16 + l16;
        bf[ni] = *(const f16x8*)&sB[nl * 64 + ((c ^ (nl & 7)) * 8)];
      }
#pragma unroll
      for (int mi = 0; mi < TM; ++mi)
#pragma unroll
        for (int ni = 0; ni < TN; ++ni)
          acc[mi][ni] = __builtin_amdgcn_mfma_f32_16x16x32_f16(
              af[mi], bf[ni], acc[mi][ni], 0, 0, 0);
    }
  }

  // Epilogue. C/D layout: col = lane&15, row = quad*4 + reg (m89/m91-verified).
#pragma unroll
  for (int ni = 0; ni < TN; ++ni) {
    const int nc = n0 + wn * WN + ni * 16 + l16;
    const float bv = HAS_BIAS ? bias[nc] : 0.0f;
#pragma unroll
    for (int mi = 0; mi < TM; ++mi) {
#pragma unroll
      for (int r = 0; r < 4; ++r) {
        const int mr = m0 + wm * WM + mi * 16 + quad * 4 + r;
        float v = acc[mi][ni][r] + bv;
        if (RELU) v = fmaxf(v, 0.0f);
        C[(size_t)mr * N + nc] = (f16)v;
      }
    }
  }
}

// ---------------------------------------------------------------------------
// Band mix: h[b,s,:] = sum_t adjn[s,t]*sup[b,t,:] + bias, optional ReLU.
// adjn = D^-1/2 (I + offdiag) D^-1/2; deg=2 at s in {0,S-1}, else 3.
// One thread per 8 halfs. S=2048, H=512 hard-coded.
// ---------------------------------------------------------------------------
__global__ __launch_bounds__(256) void band_mix_kernel(
    const f16* __restrict__ sup, f16* __restrict__ h,
    const float* __restrict__ bias, int relu)
{
  const int idx = blockIdx.x * 256 + threadIdx.x;   // chunk of 8 halfs
  const int row = idx >> 6;                          // 64 chunks per 512-half row
  const int ch  = idx & 63;
  const int s   = row & 2047;
  const float dM = 0.57735026919f;   // (3+1e-8)^-1/2 (1e-8 below fp32 eps)
  const float dE = 0.70710678118f;   // (2+1e-8)^-1/2
  const float ds = (s == 0 || s == 2047) ? dE : dM;
  const size_t off = ((size_t)row << 9) + ((size_t)ch << 3);

  f16x8 self = *(const f16x8*)(sup + off);
  float o[8];
  const float cs = ds * ds;
#pragma unroll
  for (int j = 0; j < 8; ++j) o[j] = cs * (float)self[j];
  if (s > 0) {
    const float dt = (s - 1 == 0) ? dE : dM;
    const float cp = ds * dt;
    f16x8 pv = *(const f16x8*)(sup + off - 512);
#pragma unroll
    for (int j = 0; j < 8; ++j) o[j] += cp * (float)pv[j];
  }
  if (s < 2047) {
    const float dt = (s + 1 == 2047) ? dE : dM;
    const float cn = ds * dt;
    f16x8 nx = *(const f16x8*)(sup + off + 512);
#pragma unroll
    for (int j = 0; j < 8; ++j) o[j] += cn * (float)nx[j];
  }
  f16x8 res;
#pragma unroll
  for (int j = 0; j < 8; ++j) {
    float v = o[j] + bias[(ch << 3) + j];
    if (relu) v = fmaxf(v, 0.0f);
    res[j] = (f16)v;
  }
  *(f16x8*)(h + off) = res;
}

// ---------------------------------------------------------------------------
// Head: out[row] = sigmoid(dot(z2[row,:128], w) + b). 16 lanes per row.
// ---------------------------------------------------------------------------
__global__ __launch_bounds__(256) void head_kernel(
    const f16* __restrict__ z2, const float* __restrict__ w,
    const float* __restrict__ b, float* __restrict__ out)
{
  const int tid = threadIdx.x;
  const int row = blockIdx.x * 16 + (tid >> 4);
  const int ch  = tid & 15;
  f16x8 z = *(const f16x8*)(z2 + ((size_t)row << 7) + ((size_t)ch << 3));
  float p = 0.f;
#pragma unroll
  for (int j = 0; j < 8; ++j) p += (float)z[j] * w[(ch << 3) + j];
  p += __shfl_xor(p, 1, 16);
  p += __shfl_xor(p, 2, 16);
  p += __shfl_xor(p, 4, 16);
  p += __shfl_xor(p, 8, 16);
  if (ch == 0) out[row] = 1.0f / (1.0f + expf(-(p + b[0])));
}

// ---------------------------------------------------------------------------
// Converters
// ---------------------------------------------------------------------------
__global__ __launch_bounds__(256) void cvt_x_kernel(
    const float* __restrict__ x, f16* __restrict__ xh, int n8)
{
  const int i = blockIdx.x * 256 + threadIdx.x;
  if (i >= n8) return;
  const float4* p = (const float4*)(x + ((size_t)i << 3));
  float4 a = p[0], bq = p[1];
  f16x8 o;
  o[0] = (f16)a.x;  o[1] = (f16)a.y;  o[2] = (f16)a.z;  o[3] = (f16)a.w;
  o[4] = (f16)bq.x; o[5] = (f16)bq.y; o[6] = (f16)bq.z; o[7] = (f16)bq.w;
  *(f16x8*)(xh + ((size_t)i << 3)) = o;
}

__global__ __launch_bounds__(256) void cvt_T_kernel(
    const float* __restrict__ W, f16* __restrict__ WT, int K, int N)
{
  const int idx = blockIdx.x * 256 + threadIdx.x;
  if (idx >= K * N) return;
  const int k = idx / N;
  const int n = idx - k * N;
  WT[(size_t)n * K + k] = (f16)W[idx];
}

// ---------------------------------------------------------------------------
extern "C" void kernel_launch(void* const* d_in, const int* in_sizes, int n_in,
                              void* d_out, int out_size, void* d_ws, size_t ws_size,
                              hipStream_t stream) {
  (void)in_sizes; (void)n_in; (void)out_size; (void)ws_size;
  const float* x   = (const float*)d_in[0];   // [8,2048,1024]
  const float* Wp  = (const float*)d_in[1];   // [1024,512]
  const float* bp  = (const float*)d_in[2];   // [512]
  const float* gW  = (const float*)d_in[3];   // [3,512,512]
  const float* gb  = (const float*)d_in[4];   // [3,512]
  const float* s1W = (const float*)d_in[5];   // [512,256]
  const float* s1b = (const float*)d_in[6];   // [256]
  const float* s2W = (const float*)d_in[7];   // [256,128]
  const float* s2b = (const float*)d_in[8];   // [128]
  const float* s3W = (const float*)d_in[9];   // [128,1] -> vector[128]
  const float* s3b = (const float*)d_in[10];  // [1]
  float* out = (float*)d_out;                 // [8,2048]

  constexpr int M = 16384;   // B*S
  char* ws = (char*)d_ws;
  // Region A (32MB): xh first; reused for support / z1 / z2 after proj GEMM.
  f16* xh  = (f16*)(ws + 0);                      // 16384x1024
  f16* sup = (f16*)(ws + 0);                      // 16384x512 (reuse, xh dead)
  f16* z1  = (f16*)(ws + 16777216);               // 16384x256
  f16* z2  = (f16*)(ws + 25165824);               // 16384x128
  f16* h   = (f16*)(ws + 33554432);               // 16384x512
  f16* WpT = (f16*)(ws + 50331648);               // [512,1024]
  f16* G0T = (f16*)(ws + 51380224);               // [512,512] x3
  f16* G1T = (f16*)(ws + 51904512);
  f16* G2T = (f16*)(ws + 52428800);
  f16* S1T = (f16*)(ws + 52953088);               // [256,512]
  f16* S2T = (f16*)(ws + 53215232);               // [128,256]
  f16* GT[3] = {G0T, G1T, G2T};

  // --- convert inputs to fp16 (weights transposed to [N,K]) ---
  cvt_x_kernel<<<8192, 256, 0, stream>>>(x, xh, 2097152);
  cvt_T_kernel<<<2048, 256, 0, stream>>>(Wp, WpT, 1024, 512);
  for (int i = 0; i < 3; ++i)
    cvt_T_kernel<<<1024, 256, 0, stream>>>(gW + (size_t)i * 262144, GT[i], 512, 512);
  cvt_T_kernel<<<512, 256, 0, stream>>>(s1W, S1T, 512, 256);
  cvt_T_kernel<<<128, 256, 0, stream>>>(s2W, S2T, 256, 128);

  // --- projection: h = x @ Wp + bp ---
  gemm_f16_kernel<128, 128, 2, 2, false, true>
      <<<dim3(M / 128, 4), 256, 0, stream>>>(xh, WpT, h, bp, M, 512, 1024);

  // --- GCN layers ---
  for (int i = 0; i < 3; ++i) {
    gemm_f16_kernel<128, 128, 2, 2, false, false>
        <<<dim3(M / 128, 4), 256, 0, stream>>>(h, GT[i], sup, nullptr, M, 512, 512);
    band_mix_kernel<<<4096, 256, 0, stream>>>(sup, h, gb + (size_t)i * 512, (i < 2) ? 1 : 0);
  }

  // --- score head ---
  gemm_f16_kernel<128, 128, 2, 2, true, true>
      <<<dim3(M / 128, 2), 256, 0, stream>>>(h, S1T, z1, s1b, M, 256, 512);
  gemm_f16_kernel<128, 64, 4, 1, true, true>
      <<<dim3(M / 128, 2), 256, 0, stream>>>(z1, S2T, z2, s2b, M, 128, 256);
  head_kernel<<<M / 16, 256, 0, stream>>>(z2, s3W, s3b, out);
}

// Round 2
// 233.892 us; speedup vs baseline: 1.1068x; 1.1068x over previous
//
#include <hip/hip_runtime.h>
#include <hip/hip_fp16.h>
#include <cstdint>
#include <cstddef>

// VideoSAGE: prep(cvt+transpose) -> proj GEMM -> 3x (GCN GEMM + band mix) -> fused head
// fp16 MFMA (16x16x32) with fp32 accumulate. GEMMs consume A[M,K] / BT[N,K], K-major.

typedef _Float16 f16;
typedef _Float16 f16x8 __attribute__((ext_vector_type(8)));
typedef float    f32x4 __attribute__((ext_vector_type(4)));

__device__ __forceinline__ void async_cp16(const void* g, void* l) {
  __builtin_amdgcn_global_load_lds((const __attribute__((address_space(1))) void*)g,
                                   (__attribute__((address_space(3))) void*)l, 16, 0, 0);
}

// ---------------------------------------------------------------------------
// Main GEMM: C[M,N] = act(A[M,K] * BT[N,K]^T + bias)
// 256 threads = 4 waves; XOR chunk-swizzled LDS (swizzle on GLOBAL chunk index
// so global_load_lds's lane-linear LDS dest is preserved — m104 caveat).
// ---------------------------------------------------------------------------
template<int BM, int BN, int WAVES_M, int WAVES_N, bool RELU, bool HAS_BIAS>
__global__ __launch_bounds__(256) void gemm_f16_kernel(
    const f16* __restrict__ A, const f16* __restrict__ BT,
    f16* __restrict__ C, const float* __restrict__ bias,
    int M, int N, int K)
{
  constexpr int BK = 64;
  constexpr int WM = BM / WAVES_M;
  constexpr int WN = BN / WAVES_N;
  constexpr int TM = WM / 16;
  constexpr int TN = WN / 16;
  constexpr int ITER_A = (BM * BK) / (256 * 8);
  constexpr int ITER_B = (BN * BK) / (256 * 8);

  __shared__ __align__(16) f16 sA[BM * BK];
  __shared__ __align__(16) f16 sB[BN * BK];

  const int tid  = threadIdx.x;
  const int lane = tid & 63;
  const int wave = tid >> 6;
  const int wm   = wave / WAVES_N;
  const int wn   = wave % WAVES_N;
  const int m0   = blockIdx.x * BM;
  const int n0   = blockIdx.y * BN;

  f32x4 acc[TM][TN];
#pragma unroll
  for (int i = 0; i < TM; ++i)
#pragma unroll
    for (int j = 0; j < TN; ++j)
      acc[i][j] = (f32x4){0.f, 0.f, 0.f, 0.f};

  const int quad = lane >> 4;
  const int l16  = lane & 15;

  for (int kt = 0; kt < K; kt += BK) {
    __syncthreads();
#pragma unroll
    for (int j = 0; j < ITER_A; ++j) {
      const int linear = j * 256 + tid;
      const int row = linear >> 3;
      const int q   = (linear & 7) ^ (row & 7);
      async_cp16(A + (size_t)(m0 + row) * K + kt + q * 8, &sA[linear * 8]);
    }
#pragma unroll
    for (int j = 0; j < ITER_B; ++j) {
      const int linear = j * 256 + tid;
      const int row = linear >> 3;
      const int q   = (linear & 7) ^ (row & 7);
      async_cp16(BT + (size_t)(n0 + row) * K + kt + q * 8, &sB[linear * 8]);
    }
    __syncthreads();

#pragma unroll
    for (int kk = 0; kk < 2; ++kk) {
      const int c = quad + kk * 4;
      f16x8 af[TM], bf[TN];
#pragma unroll
      for (int mi = 0; mi < TM; ++mi) {
        const int ml = wm * WM + mi * 16 + l16;
        af[mi] = *(const f16x8*)&sA[ml * 64 + ((c ^ (ml & 7)) * 8)];
      }
#pragma unroll
      for (int ni = 0; ni < TN; ++ni) {
        const int nl = wn * WN + ni * 16 + l16;
        bf[ni] = *(const f16x8*)&sB[nl * 64 + ((c ^ (nl & 7)) * 8)];
      }
#pragma unroll
      for (int mi = 0; mi < TM; ++mi)
#pragma unroll
        for (int ni = 0; ni < TN; ++ni)
          acc[mi][ni] = __builtin_amdgcn_mfma_f32_16x16x32_f16(
              af[mi], bf[ni], acc[mi][ni], 0, 0, 0);
    }
  }

  // C/D layout: col = lane&15, row = quad*4 + reg (m89/m91-verified).
#pragma unroll
  for (int ni = 0; ni < TN; ++ni) {
    const int nc = n0 + wn * WN + ni * 16 + l16;
    const float bv = HAS_BIAS ? bias[nc] : 0.0f;
#pragma unroll
    for (int mi = 0; mi < TM; ++mi) {
#pragma unroll
      for (int r = 0; r < 4; ++r) {
        const int mr = m0 + wm * WM + mi * 16 + quad * 4 + r;
        float v = acc[mi][ni][r] + bv;
        if (RELU) v = fmaxf(v, 0.0f);
        C[(size_t)mr * N + nc] = (f16)v;
      }
    }
  }
}

// ---------------------------------------------------------------------------
// Band mix: h[b,s,:] = sum_t adjn[s,t]*sup[b,t,:] + bias, optional ReLU.
// ---------------------------------------------------------------------------
__global__ __launch_bounds__(256) void band_mix_kernel(
    const f16* __restrict__ sup, f16* __restrict__ h,
    const float* __restrict__ bias, int relu)
{
  const int idx = blockIdx.x * 256 + threadIdx.x;
  const int row = idx >> 6;
  const int ch  = idx & 63;
  const int s   = row & 2047;
  const float dM = 0.57735026919f;   // (3+1e-8)^-1/2
  const float dE = 0.70710678118f;   // (2+1e-8)^-1/2
  const float ds = (s == 0 || s == 2047) ? dE : dM;
  const size_t off = ((size_t)row << 9) + ((size_t)ch << 3);

  f16x8 self = *(const f16x8*)(sup + off);
  float o[8];
  const float cs = ds * ds;
#pragma unroll
  for (int j = 0; j < 8; ++j) o[j] = cs * (float)self[j];
  if (s > 0) {
    const float cp = ds * ((s - 1 == 0) ? dE : dM);
    f16x8 pv = *(const f16x8*)(sup + off - 512);
#pragma unroll
    for (int j = 0; j < 8; ++j) o[j] += cp * (float)pv[j];
  }
  if (s < 2047) {
    const float cn = ds * ((s + 1 == 2047) ? dE : dM);
    f16x8 nx = *(const f16x8*)(sup + off + 512);
#pragma unroll
    for (int j = 0; j < 8; ++j) o[j] += cn * (float)nx[j];
  }
  f16x8 res;
#pragma unroll
  for (int j = 0; j < 8; ++j) {
    float v = o[j] + bias[(ch << 3) + j];
    if (relu) v = fmaxf(v, 0.0f);
    res[j] = (f16)v;
  }
  *(f16x8*)(h + off) = res;
}

// ---------------------------------------------------------------------------
// Fused head: per 64-row block, z1=relu(h@S1T^T+b1) in LDS -> z2=relu(z1@S2T^T+b2)
// in LDS -> out=sigmoid(z2.w+b3). Saves z1/z2 global round-trips + 2 launches.
// LDS: R1 = sA(8K)+sB(32K) = 40KB, reused for z2s(17K)+sB2(16K); zs = 33KB.
// Total ~73KB -> 2 blocks/CU.
// ---------------------------------------------------------------------------
__global__ __launch_bounds__(256) void head_fused_kernel(
    const f16* __restrict__ h, const f16* __restrict__ S1T,
    const f16* __restrict__ S2T,
    const float* __restrict__ s1b, const float* __restrict__ s2b,
    const float* __restrict__ s3w, const float* __restrict__ s3b,
    float* __restrict__ out)
{
  __shared__ __align__(16) char smem[40960 + 64 * 264 * 2];
  f16* sA  = (f16*)smem;             // [64*64]
  f16* sB  = (f16*)(smem + 8192);    // [256*64]
  f16* zs  = (f16*)(smem + 40960);   // [64][264] padded (granule stride 33: conflict-free)
  f16* z2s = (f16*)smem;             // [64][136] (reuses sA region)
  f16* sB2 = (f16*)(smem + 17408);   // [128*64]  (reuses sB region)

  const int tid  = threadIdx.x;
  const int lane = tid & 63;
  const int wave = tid >> 6;
  const int quad = lane >> 4;
  const int l16  = lane & 15;
  const int m0   = blockIdx.x * 64;

  // ---- GEMM1: z1[64][256] = relu(h[64x512] @ S1T^T + s1b), wave = 64x64 tile ----
  f32x4 acc[4][4];
#pragma unroll
  for (int i = 0; i < 4; ++i)
#pragma unroll
    for (int j = 0; j < 4; ++j) acc[i][j] = (f32x4){0.f, 0.f, 0.f, 0.f};

  for (int kt = 0; kt < 512; kt += 64) {
    __syncthreads();
#pragma unroll
    for (int j = 0; j < 2; ++j) {          // A: 64x64 halfs = 512 chunks
      const int linear = j * 256 + tid;
      const int row = linear >> 3;
      const int q   = (linear & 7) ^ (row & 7);
      async_cp16(h + (size_t)(m0 + row) * 512 + kt + q * 8, &sA[linear * 8]);
    }
#pragma unroll
    for (int j = 0; j < 8; ++j) {          // B: 256x64 halfs = 2048 chunks
      const int linear = j * 256 + tid;
      const int row = linear >> 3;
      const int q   = (linear & 7) ^ (row & 7);
      async_cp16(S1T + (size_t)row * 512 + kt + q * 8, &sB[linear * 8]);
    }
    __syncthreads();
#pragma unroll
    for (int kk = 0; kk < 2; ++kk) {
      const int c = quad + kk * 4;
      f16x8 af[4], bf[4];
#pragma unroll
      for (int mi = 0; mi < 4; ++mi) {
        const int ml = mi * 16 + l16;
        af[mi] = *(const f16x8*)&sA[ml * 64 + ((c ^ (ml & 7)) * 8)];
      }
#pragma unroll
      for (int ni = 0; ni < 4; ++ni) {
        const int nl = wave * 64 + ni * 16 + l16;
        bf[ni] = *(const f16x8*)&sB[nl * 64 + ((c ^ (nl & 7)) * 8)];
      }
#pragma unroll
      for (int mi = 0; mi < 4; ++mi)
#pragma unroll
        for (int ni = 0; ni < 4; ++ni)
          acc[mi][ni] = __builtin_amdgcn_mfma_f32_16x16x32_f16(
              af[mi], bf[ni], acc[mi][ni], 0, 0, 0);
    }
  }
  // epilogue 1 -> zs (row-major, pad 264)
#pragma unroll
  for (int ni = 0; ni < 4; ++ni) {
    const int nc = wave * 64 + ni * 16 + l16;
    const float bv = s1b[nc];
#pragma unroll
    for (int mi = 0; mi < 4; ++mi)
#pragma unroll
      for (int r = 0; r < 4; ++r) {
        const int row = mi * 16 + quad * 4 + r;
        zs[row * 264 + nc] = (f16)fmaxf(acc[mi][ni][r] + bv, 0.0f);
      }
  }
  __syncthreads();

  // ---- GEMM2: z2[64][128] = relu(z1 @ S2T^T + s2b), wave = 64x32 cols ----
  f32x4 acc2[4][2];
#pragma unroll
  for (int i = 0; i < 4; ++i)
#pragma unroll
    for (int j = 0; j < 2; ++j) acc2[i][j] = (f32x4){0.f, 0.f, 0.f, 0.f};

  for (int kt2 = 0; kt2 < 4; ++kt2) {      // K=256, BK=64
    __syncthreads();
#pragma unroll
    for (int j = 0; j < 4; ++j) {          // B2: 128x64 halfs = 1024 chunks
      const int linear = j * 256 + tid;
      const int row = linear >> 3;
      const int q   = (linear & 7) ^ (row & 7);
      async_cp16(S2T + (size_t)row * 256 + kt2 * 64 + q * 8, &sB2[linear * 8]);
    }
    __syncthreads();
#pragma unroll
    for (int kk = 0; kk < 2; ++kk) {
      const int c = quad + kk * 4;
      f16x8 af[4], bf[2];
#pragma unroll
      for (int mi = 0; mi < 4; ++mi) {
        const int row = mi * 16 + l16;
        af[mi] = *(const f16x8*)&zs[row * 264 + (kt2 * 8 + c) * 8];
      }
#pragma unroll
      for (int ni = 0; ni < 2; ++ni) {
        const int nl = wave * 32 + ni * 16 + l16;
        bf[ni] = *(const f16x8*)&sB2[nl * 64 + ((c ^ (nl & 7)) * 8)];
      }
#pragma unroll
      for (int mi = 0; mi < 4; ++mi)
#pragma unroll
        for (int ni = 0; ni < 2; ++ni)
          acc2[mi][ni] = __builtin_amdgcn_mfma_f32_16x16x32_f16(
              af[mi], bf[ni], acc2[mi][ni], 0, 0, 0);
    }
  }
  __syncthreads();   // all sB2 reads done before z2s (aliases sA region only) writes race? no alias; still order head reads
  // epilogue 2 -> z2s (pad 136)
#pragma unroll
  for (int ni = 0; ni < 2; ++ni) {
    const int nc = wave * 32 + ni * 16 + l16;
    const float bv = s2b[nc];
#pragma unroll
    for (int mi = 0; mi < 4; ++mi)
#pragma unroll
      for (int r = 0; r < 4; ++r) {
        const int row = mi * 16 + quad * 4 + r;
        z2s[row * 136 + nc] = (f16)fmaxf(acc2[mi][ni][r] + bv, 0.0f);
      }
  }
  __syncthreads();

  // ---- head: out[m] = sigmoid(dot(z2[m], w) + b), 4 threads/row ----
  const int m = tid >> 2;
  const int qd = tid & 3;
  float p = 0.f;
#pragma unroll
  for (int j = 0; j < 4; ++j) {
    f16x8 v = *(const f16x8*)&z2s[m * 136 + qd * 32 + j * 8];
#pragma unroll
    for (int e = 0; e < 8; ++e) p += (float)v[e] * s3w[qd * 32 + j * 8 + e];
  }
  p += __shfl_xor(p, 1);
  p += __shfl_xor(p, 2);
  if (qd == 0) out[m0 + m] = 1.0f / (1.0f + expf(-(p + s3b[0])));
}

// ---------------------------------------------------------------------------
// Prep: cvt x -> fp16 (blocks 0..8191), then 64x64 tile-transposes of all
// weights (coalesced read AND write via LDS tile).
// ---------------------------------------------------------------------------
__global__ __launch_bounds__(256) void prep_kernel(
    const float* __restrict__ x, f16* __restrict__ xh,
    const float* __restrict__ Wp, f16* __restrict__ WpT,
    const float* __restrict__ gW, f16* __restrict__ GT,
    const float* __restrict__ s1W, f16* __restrict__ S1T,
    const float* __restrict__ s2W, f16* __restrict__ S2T)
{
  __shared__ f16 s[64 * 68];
  const int tid = threadIdx.x;
  int b = blockIdx.x;

  if (b < 8192) {            // x: 2097152 chunks of 8
    const int i = b * 256 + tid;
    const float4* p = (const float4*)(x + ((size_t)i << 3));
    float4 a = p[0], bq = p[1];
    f16x8 o;
    o[0] = (f16)a.x;  o[1] = (f16)a.y;  o[2] = (f16)a.z;  o[3] = (f16)a.w;
    o[4] = (f16)bq.x; o[5] = (f16)bq.y; o[6] = (f16)bq.z; o[7] = (f16)bq.w;
    *(f16x8*)(xh + ((size_t)i << 3)) = o;
    return;
  }
  b -= 8192;
  const float* W; f16* WT; int K, N, tile;
  if (b < 128)      { W = Wp;  WT = WpT; K = 1024; N = 512; tile = b; }
  else if (b < 320) { const int i = (b - 128) >> 6;
                      W = gW + (size_t)i * 262144; WT = GT + (size_t)i * 262144;
                      K = 512; N = 512; tile = (b - 128) & 63; }
  else if (b < 352) { W = s1W; WT = S1T; K = 512; N = 256; tile = b - 320; }
  else              { W = s2W; WT = S2T; K = 256; N = 128; tile = b - 352; }

  const int nt = tile % (N >> 6);
  const int kt = tile / (N >> 6);
#pragma unroll
  for (int it = 0; it < 16; ++it) {       // read: consecutive tid -> consecutive n
    const int i  = it * 256 + tid;
    const int rk = i >> 6, rn = i & 63;
    s[rn * 68 + rk] = (f16)W[(size_t)(kt * 64 + rk) * N + nt * 64 + rn];
  }
  __syncthreads();
#pragma unroll
  for (int it = 0; it < 16; ++it) {       // write: consecutive tid -> consecutive k
    const int i  = it * 256 + tid;
    const int rn = i >> 6, rk = i & 63;
    WT[(size_t)(nt * 64 + rn) * K + kt * 64 + rk] = s[rn * 68 + rk];
  }
}

// ---------------------------------------------------------------------------
extern "C" void kernel_launch(void* const* d_in, const int* in_sizes, int n_in,
                              void* d_out, int out_size, void* d_ws, size_t ws_size,
                              hipStream_t stream) {
  (void)in_sizes; (void)n_in; (void)out_size; (void)ws_size;
  const float* x   = (const float*)d_in[0];
  const float* Wp  = (const float*)d_in[1];
  const float* bp  = (const float*)d_in[2];
  const float* gW  = (const float*)d_in[3];
  const float* gb  = (const float*)d_in[4];
  const float* s1W = (const float*)d_in[5];
  const float* s1b = (const float*)d_in[6];
  const float* s2W = (const float*)d_in[7];
  const float* s2b = (const float*)d_in[8];
  const float* s3W = (const float*)d_in[9];
  const float* s3b = (const float*)d_in[10];
  float* out = (float*)d_out;

  constexpr int M = 16384;
  char* ws = (char*)d_ws;
  f16* xh  = (f16*)(ws + 0);            // 16384x1024 (dead after proj)
  f16* sup = (f16*)(ws + 0);            // 16384x512 (reuse)
  f16* h   = (f16*)(ws + 33554432);     // 16384x512
  f16* WpT = (f16*)(ws + 50331648);     // [512,1024]
  f16* GT  = (f16*)(ws + 51380224);     // 3x[512,512] contiguous
  f16* S1T = (f16*)(ws + 52953088);     // [256,512]
  f16* S2T = (f16*)(ws + 53215232);     // [128,256]

  prep_kernel<<<8552, 256, 0, stream>>>(x, xh, Wp, WpT, gW, GT, s1W, S1T, s2W, S2T);

  gemm_f16_kernel<128, 128, 2, 2, false, true>
      <<<dim3(M / 128, 4), 256, 0, stream>>>(xh, WpT, h, bp, M, 512, 1024);

  for (int i = 0; i < 3; ++i) {
    gemm_f16_kernel<128, 128, 2, 2, false, false>
        <<<dim3(M / 128, 4), 256, 0, stream>>>(h, GT + (size_t)i * 262144, sup,
                                               nullptr, M, 512, 512);
    band_mix_kernel<<<4096, 256, 0, stream>>>(sup, h, gb + (size_t)i * 512, (i < 2) ? 1 : 0);
  }

  head_fused_kernel<<<M / 64, 256, 0, stream>>>(h, S1T, S2T, s1b, s2b, s3W, s3b, out);
}